// Round 3
// baseline (3651.666 us; speedup 1.0000x reference)
//
#include <hip/hip_runtime.h>

#define N_USER 100000
#define N_ITEM 200000
#define N_TOT  (N_USER + N_ITEM)
#define D      64
#define RPB    64                       // rows per bucket
#define NB     ((N_TOT + RPB - 1) / RPB)  // 4688 buckets
#define NBLK_A 96                       // blocks for hist/bin passes
#define THR_A  512

// ---------- K1: per-block bucket histogram (LDS-aggregated, no global atomics) ----------
__global__ __launch_bounds__(THR_A) void hist_kernel(const int* __restrict__ rows,
                                                     int* __restrict__ hist, int nnz, int chunk) {
    __shared__ int h[NB];
    for (int k = threadIdx.x; k < NB; k += blockDim.x) h[k] = 0;
    __syncthreads();
    int lo = blockIdx.x * chunk;
    int hi = min(lo + chunk, nnz);
    for (int i = lo + threadIdx.x; i < hi; i += blockDim.x)
        atomicAdd(&h[rows[i] >> 6], 1);
    __syncthreads();
    for (int k = threadIdx.x; k < NB; k += blockDim.x)
        hist[(size_t)blockIdx.x * NB + k] = h[k];
}

// ---------- K2: bucket totals ----------
__global__ void bucket_tot_kernel(const int* __restrict__ hist, int* __restrict__ tot) {
    int k = blockIdx.x * blockDim.x + threadIdx.x;
    if (k >= NB) return;
    int s = 0;
    for (int b = 0; b < NBLK_A; ++b) s += hist[(size_t)b * NB + k];
    tot[k] = s;
}

// ---------- K3: exclusive scan of bucket totals -> bstart ----------
__global__ __launch_bounds__(1024) void scan_kernel(const int* __restrict__ tot,
                                                    int* __restrict__ bstart, int nnz) {
    __shared__ int s[1024];
    const int t = threadIdx.x;
    const int PER = (NB + 1023) / 1024;   // 5
    int loc[8];
    int sum = 0;
    #pragma unroll
    for (int k = 0; k < PER; ++k) {
        int idx = t * PER + k;
        int v = (idx < NB) ? tot[idx] : 0;
        loc[k] = sum; sum += v;
    }
    s[t] = sum;
    __syncthreads();
    for (int off = 1; off < 1024; off <<= 1) {
        int v = (t >= off) ? s[t - off] : 0;
        __syncthreads();
        s[t] += v;
        __syncthreads();
    }
    int base = s[t] - sum;  // exclusive
    #pragma unroll
    for (int k = 0; k < PER; ++k) {
        int idx = t * PER + k;
        if (idx < NB) bstart[idx] = base + loc[k];
    }
    if (t == 1023) bstart[NB] = nnz;
}

// ---------- K4: per-(block,bucket) write bases, in place on hist ----------
__global__ void blockbase_kernel(int* __restrict__ hist, const int* __restrict__ bstart) {
    int k = blockIdx.x * blockDim.x + threadIdx.x;
    if (k >= NB) return;
    int base = bstart[k];
    for (int b = 0; b < NBLK_A; ++b) {
        size_t idx = (size_t)b * NB + k;
        int v = hist[idx];
        hist[idx] = base;
        base += v;
    }
}

// ---------- K5: bin edges into bucket regions (LDS cursors, no global atomics) ----------
__global__ __launch_bounds__(THR_A) void bin_kernel(const int* __restrict__ rows,
                                                    const int* __restrict__ cols,
                                                    const float* __restrict__ vals,
                                                    const int* __restrict__ hist,
                                                    uint2* __restrict__ eg, int nnz, int chunk) {
    __shared__ int cur[NB];
    for (int k = threadIdx.x; k < NB; k += blockDim.x)
        cur[k] = hist[(size_t)blockIdx.x * NB + k];
    __syncthreads();
    int lo = blockIdx.x * chunk;
    int hi = min(lo + chunk, nnz);
    for (int i = lo + threadIdx.x; i < hi; i += blockDim.x) {
        int r = rows[i];
        int k = r >> 6;
        int slot = atomicAdd(&cur[k], 1);
        uint2 p;
        p.x = ((unsigned)(r & 63) << 19) | (unsigned)cols[i];
        p.y = __float_as_uint(vals[i]);
        eg[slot] = p;
    }
}

// ---------- K6: fused per-bucket LDS accumulate + base + neighbor + writeout ----------
__global__ __launch_bounds__(512) void bucket_gather(
    const float* __restrict__ users, const float* __restrict__ items,
    const int*   __restrict__ unb,   const float* __restrict__ uw,
    const int*   __restrict__ inb,   const float* __restrict__ iw,
    const int*   __restrict__ bstart, const uint2* __restrict__ eg,
    float* __restrict__ out)
{
    __shared__ float acc[RPB * D];   // 16 KB
    const int tid  = threadIdx.x;
    const int wave = tid >> 6;
    const int lane = tid & 63;
    const int k    = blockIdx.x;

    for (int j = tid; j < RPB * D; j += blockDim.x) acc[j] = 0.0f;
    __syncthreads();

    const int s = bstart[k];
    const int e = bstart[k + 1];
    const int cnt = e - s;
    const int per = (cnt + 7) >> 3;       // 8 waves
    const int ws = s + wave * per;
    const int we = min(ws + per, e);

    #pragma unroll 4
    for (int i = ws; i < we; ++i) {
        uint2 p = eg[i];
        int col = (int)(p.x & 0x7FFFFu);
        int ro  = (int)(p.x >> 19);
        float v = __uint_as_float(p.y);
        const float* src = (col < N_USER) ? users + (size_t)col * D
                                          : items + (size_t)(col - N_USER) * D;
        atomicAdd(&acc[ro * D + lane], v * src[lane]);
    }
    __syncthreads();

    const int row0 = k * RPB;
    for (int j = wave; j < RPB; j += 8) {
        int row = row0 + j;
        if (row >= N_TOT) break;
        float a = acc[j * D + lane];
        if (row < N_USER) {
            a += users[(size_t)row * D + lane];
            const int*   nb = unb + (size_t)row * 10;
            const float* w  = uw  + (size_t)row * 10;
            #pragma unroll
            for (int q = 0; q < 10; ++q) a += w[q] * users[(size_t)nb[q] * D + lane];
        } else {
            int r = row - N_USER;
            a += items[(size_t)r * D + lane];
            const int*   nb = inb + (size_t)r * 10;
            const float* w  = iw  + (size_t)r * 10;
            #pragma unroll
            for (int q = 0; q < 10; ++q) a += w[q] * items[(size_t)nb[q] * D + lane];
        }
        out[(size_t)row * D + lane] = a;
    }
}

// ---------- fallback (round-1) scatter path ----------
__global__ __launch_bounds__(256) void base_neighbor_kernel(
    const float* __restrict__ users, const float* __restrict__ items,
    const int*   __restrict__ unb,   const float* __restrict__ uw,
    const int*   __restrict__ inb,   const float* __restrict__ iw,
    float* __restrict__ out)
{
    int gtid = blockIdx.x * blockDim.x + threadIdx.x;
    int row  = gtid >> 6;
    int lane = gtid & 63;
    if (row >= N_TOT) return;
    float acc;
    if (row < N_USER) {
        acc = users[(size_t)row * D + lane];
        const int*   nb = unb + (size_t)row * 10;
        const float* w  = uw  + (size_t)row * 10;
        #pragma unroll
        for (int q = 0; q < 10; ++q) acc += w[q] * users[(size_t)nb[q] * D + lane];
    } else {
        int r = row - N_USER;
        acc = items[(size_t)r * D + lane];
        const int*   nb = inb + (size_t)r * 10;
        const float* w  = iw  + (size_t)r * 10;
        #pragma unroll
        for (int q = 0; q < 10; ++q) acc += w[q] * items[(size_t)nb[q] * D + lane];
    }
    out[(size_t)row * D + lane] = acc;
}

__global__ __launch_bounds__(256) void edge_scatter_kernel(
    const float* __restrict__ users, const float* __restrict__ items,
    const int*   __restrict__ rows,  const int* __restrict__ cols,
    const float* __restrict__ vals,
    float* __restrict__ out, int nnz)
{
    int gtid = blockIdx.x * blockDim.x + threadIdx.x;
    int e    = gtid >> 6;
    int lane = gtid & 63;
    if (e >= nnz) return;
    int   r = rows[e];
    int   c = cols[e];
    float v = vals[e];
    const float* src = (c < N_USER) ? (users + (size_t)c * D)
                                    : (items + (size_t)(c - N_USER) * D);
    atomicAdd(&out[(size_t)r * D + lane], v * src[lane]);
}

extern "C" void kernel_launch(void* const* d_in, const int* in_sizes, int n_in,
                              void* d_out, int out_size, void* d_ws, size_t ws_size,
                              hipStream_t stream) {
    const float* users = (const float*)d_in[0];
    const float* items = (const float*)d_in[1];
    const int*   unb   = (const int*)  d_in[2];
    const float* uw    = (const float*)d_in[3];
    const int*   inb   = (const int*)  d_in[4];
    const float* iw    = (const float*)d_in[5];
    const int*   grow  = (const int*)  d_in[6];
    const int*   gcol  = (const int*)  d_in[7];
    const float* gval  = (const float*)d_in[8];
    float* out = (float*)d_out;

    const int nnz = in_sizes[6];

    // workspace layout (256B-aligned chunks)
    const size_t sz_eg     = (((size_t)nnz * 8) + 255) & ~(size_t)255;
    const size_t sz_hist   = (((size_t)NBLK_A * NB * 4) + 255) & ~(size_t)255;
    const size_t sz_tot    = (((size_t)NB * 4) + 255) & ~(size_t)255;
    const size_t sz_bstart = (((size_t)(NB + 1) * 4) + 255) & ~(size_t)255;
    const size_t need      = sz_eg + sz_hist + sz_tot + sz_bstart;

    if (ws_size >= need) {
        char* wsp = (char*)d_ws;
        uint2* eg     = (uint2*)wsp;  wsp += sz_eg;
        int*   hist   = (int*)wsp;    wsp += sz_hist;
        int*   tot    = (int*)wsp;    wsp += sz_tot;
        int*   bstart = (int*)wsp;

        const int chunk = (nnz + NBLK_A - 1) / NBLK_A;

        hist_kernel<<<NBLK_A, THR_A, 0, stream>>>(grow, hist, nnz, chunk);
        bucket_tot_kernel<<<(NB + 255) / 256, 256, 0, stream>>>(hist, tot);
        scan_kernel<<<1, 1024, 0, stream>>>(tot, bstart, nnz);
        blockbase_kernel<<<(NB + 255) / 256, 256, 0, stream>>>(hist, bstart);
        bin_kernel<<<NBLK_A, THR_A, 0, stream>>>(grow, gcol, gval, hist, eg, nnz, chunk);
        bucket_gather<<<NB, 512, 0, stream>>>(users, items, unb, uw, inb, iw,
                                              bstart, eg, out);
    } else {
        long long threads = (long long)N_TOT * 64;
        int grid = (int)((threads + 255) / 256);
        base_neighbor_kernel<<<grid, 256, 0, stream>>>(users, items, unb, uw, inb, iw, out);
        long long ethreads = (long long)nnz * 64;
        long long egrid = (ethreads + 255) / 256;
        edge_scatter_kernel<<<(int)egrid, 256, 0, stream>>>(users, items, grow, gcol, gval, out, nnz);
    }
}

// Round 4
// 1019.710 us; speedup vs baseline: 3.5811x; 3.5811x over previous
//
#include <hip/hip_runtime.h>

#define N_USER 100000
#define N_ITEM 200000
#define N_TOT  (N_USER + N_ITEM)
#define D      64
#define RPB    64                        // rows per bucket
#define NB     ((N_TOT + RPB - 1) / RPB) // 4688 buckets
#define NBLK_A 96                        // blocks for hist/bin passes
#define THR_A  512
#define SCAN_CHUNK 2048                  // tier-2 scan: 256 threads x 8

// ================= tier-1: bucket binning =================

__global__ __launch_bounds__(THR_A) void hist_kernel(const int* __restrict__ rows,
                                                     int* __restrict__ hist, int nnz, int chunk) {
    __shared__ int h[NB];
    for (int k = threadIdx.x; k < NB; k += blockDim.x) h[k] = 0;
    __syncthreads();
    int lo = blockIdx.x * chunk;
    int hi = min(lo + chunk, nnz);
    for (int i = lo + threadIdx.x; i < hi; i += blockDim.x)
        atomicAdd(&h[rows[i] >> 6], 1);
    __syncthreads();
    for (int k = threadIdx.x; k < NB; k += blockDim.x)
        hist[(size_t)blockIdx.x * NB + k] = h[k];
}

__global__ void bucket_tot_kernel(const int* __restrict__ hist, int* __restrict__ tot) {
    int k = blockIdx.x * blockDim.x + threadIdx.x;
    if (k >= NB) return;
    int s = 0;
    for (int b = 0; b < NBLK_A; ++b) s += hist[(size_t)b * NB + k];
    tot[k] = s;
}

__global__ __launch_bounds__(1024) void scan_kernel(const int* __restrict__ tot,
                                                    int* __restrict__ bstart, int nnz) {
    __shared__ int s[1024];
    const int t = threadIdx.x;
    const int PER = (NB + 1023) / 1024;   // 5
    int loc[8];
    int sum = 0;
    #pragma unroll
    for (int k = 0; k < PER; ++k) {
        int idx = t * PER + k;
        int v = (idx < NB) ? tot[idx] : 0;
        loc[k] = sum; sum += v;
    }
    s[t] = sum;
    __syncthreads();
    for (int off = 1; off < 1024; off <<= 1) {
        int v = (t >= off) ? s[t - off] : 0;
        __syncthreads();
        s[t] += v;
        __syncthreads();
    }
    int base = s[t] - sum;  // exclusive
    #pragma unroll
    for (int k = 0; k < PER; ++k) {
        int idx = t * PER + k;
        if (idx < NB) bstart[idx] = base + loc[k];
    }
    if (t == 1023) bstart[NB] = nnz;
}

__global__ void blockbase_kernel(int* __restrict__ hist, const int* __restrict__ bstart) {
    int k = blockIdx.x * blockDim.x + threadIdx.x;
    if (k >= NB) return;
    int base = bstart[k];
    for (int b = 0; b < NBLK_A; ++b) {
        size_t idx = (size_t)b * NB + k;
        int v = hist[idx];
        hist[idx] = base;
        base += v;
    }
}

__global__ __launch_bounds__(THR_A) void bin_kernel(const int* __restrict__ rows,
                                                    const int* __restrict__ cols,
                                                    const float* __restrict__ vals,
                                                    const int* __restrict__ hist,
                                                    uint2* __restrict__ eg, int nnz, int chunk) {
    __shared__ int cur[NB];
    for (int k = threadIdx.x; k < NB; k += blockDim.x)
        cur[k] = hist[(size_t)blockIdx.x * NB + k];
    __syncthreads();
    int lo = blockIdx.x * chunk;
    int hi = min(lo + chunk, nnz);
    for (int i = lo + threadIdx.x; i < hi; i += blockDim.x) {
        int r = rows[i];
        int k = r >> 6;
        int slot = atomicAdd(&cur[k], 1);
        uint2 p;
        p.x = ((unsigned)(r & 63) << 19) | (unsigned)cols[i];
        p.y = __float_as_uint(vals[i]);
        eg[slot] = p;
    }
}

// per-bucket row sort: LDS hist -> 64-lane scan -> scatter to eg2 + row_start
__global__ __launch_bounds__(256) void rowsort_kernel(
    const uint2* __restrict__ eg, const int* __restrict__ bstart,
    uint2* __restrict__ eg2, int* __restrict__ row_start, int nnz)
{
    __shared__ int h[RPB];
    __shared__ int cur[RPB];
    const int k   = blockIdx.x;
    const int tid = threadIdx.x;
    const int s   = bstart[k];
    const int e   = bstart[k + 1];

    if (tid < RPB) h[tid] = 0;
    __syncthreads();
    for (int i = s + tid; i < e; i += 256)
        atomicAdd(&h[eg[i].x >> 19], 1);
    __syncthreads();
    if (tid < RPB) {   // wave 0 only
        int orig = h[tid];
        int v = orig;
        #pragma unroll
        for (int off = 1; off < RPB; off <<= 1) {
            int u = __shfl_up(v, off);
            if (tid >= off) v += u;
        }
        int excl = v - orig;
        cur[tid] = excl;
        int row = k * RPB + tid;
        if (row < N_TOT) row_start[row] = s + excl;
    }
    __syncthreads();
    for (int i = s + tid; i < e; i += 256) {
        uint2 p = eg[i];
        int ro = (int)(p.x >> 19);
        int slot = atomicAdd(&cur[ro], 1);
        eg2[s + slot] = p;
    }
    if (k == NB - 1 && tid == 0) row_start[N_TOT] = nnz;
}

// ================= fused per-row gather (register accumulate) =================
__global__ __launch_bounds__(256) void gather_kernel(
    const float* __restrict__ users, const float* __restrict__ items,
    const int*   __restrict__ unb,   const float* __restrict__ uw,
    const int*   __restrict__ inb,   const float* __restrict__ iw,
    const int*   __restrict__ row_start, const uint2* __restrict__ eg,
    float* __restrict__ out)
{
    int gtid = blockIdx.x * blockDim.x + threadIdx.x;
    int row  = gtid >> 6;
    int lane = gtid & 63;
    if (row >= N_TOT) return;

    float acc;
    if (row < N_USER) {
        acc = users[(size_t)row * D + lane];
        const int*   nb = unb + (size_t)row * 10;
        const float* w  = uw  + (size_t)row * 10;
        #pragma unroll
        for (int k = 0; k < 10; ++k) acc += w[k] * users[(size_t)nb[k] * D + lane];
    } else {
        int r = row - N_USER;
        acc = items[(size_t)r * D + lane];
        const int*   nb = inb + (size_t)r * 10;
        const float* w  = iw  + (size_t)r * 10;
        #pragma unroll
        for (int k = 0; k < 10; ++k) acc += w[k] * items[(size_t)nb[k] * D + lane];
    }

    int s = row_start[row];
    int e = row_start[row + 1];
    int i = s;
    for (; i + 3 < e; i += 4) {
        uint2 e0 = eg[i], e1 = eg[i + 1], e2 = eg[i + 2], e3 = eg[i + 3];
        int c0 = (int)(e0.x & 0x7FFFFu), c1 = (int)(e1.x & 0x7FFFFu);
        int c2 = (int)(e2.x & 0x7FFFFu), c3 = (int)(e3.x & 0x7FFFFu);
        const float* s0 = (c0 < N_USER) ? users + (size_t)c0 * D : items + (size_t)(c0 - N_USER) * D;
        const float* s1 = (c1 < N_USER) ? users + (size_t)c1 * D : items + (size_t)(c1 - N_USER) * D;
        const float* s2 = (c2 < N_USER) ? users + (size_t)c2 * D : items + (size_t)(c2 - N_USER) * D;
        const float* s3 = (c3 < N_USER) ? users + (size_t)c3 * D : items + (size_t)(c3 - N_USER) * D;
        float v0 = s0[lane], v1 = s1[lane], v2 = s2[lane], v3 = s3[lane];
        acc += __uint_as_float(e0.y) * v0;
        acc += __uint_as_float(e1.y) * v1;
        acc += __uint_as_float(e2.y) * v2;
        acc += __uint_as_float(e3.y) * v3;
    }
    for (; i < e; ++i) {
        uint2 ed = eg[i];
        int c = (int)(ed.x & 0x7FFFFu);
        const float* src = (c < N_USER) ? users + (size_t)c * D : items + (size_t)(c - N_USER) * D;
        acc += __uint_as_float(ed.y) * src[lane];
    }

    out[(size_t)row * D + lane] = acc;
}

// ================= tier-2: round-2 CSR build =================

__global__ void count_kernel(const int* __restrict__ rows, int* __restrict__ cnt, int nnz) {
    int i = blockIdx.x * blockDim.x + threadIdx.x;
    int stride = gridDim.x * blockDim.x;
    for (; i < nnz; i += stride) atomicAdd(&cnt[rows[i]], 1);
}

__global__ void scan_block_sums(const int* __restrict__ cnt, int* __restrict__ bsum, int n) {
    __shared__ int sdata[256];
    int base = blockIdx.x * SCAN_CHUNK;
    int s = 0;
    for (int t = threadIdx.x; t < SCAN_CHUNK; t += 256) {
        int idx = base + t;
        s += (idx < n) ? cnt[idx] : 0;
    }
    sdata[threadIdx.x] = s;
    __syncthreads();
    for (int off = 128; off > 0; off >>= 1) {
        if (threadIdx.x < off) sdata[threadIdx.x] += sdata[threadIdx.x + off];
        __syncthreads();
    }
    if (threadIdx.x == 0) bsum[blockIdx.x] = sdata[0];
}

__global__ void scan_bsum_kernel(int* __restrict__ bsum, int nb) {
    if (threadIdx.x == 0 && blockIdx.x == 0) {
        int acc = 0;
        for (int i = 0; i < nb; ++i) { int v = bsum[i]; bsum[i] = acc; acc += v; }
    }
}

__global__ void scan_final(const int* __restrict__ cnt, const int* __restrict__ bsum,
                           int* __restrict__ row_start, int n, int nnz) {
    __shared__ int sums[256];
    int b = blockIdx.x, t = threadIdx.x;
    int base = b * SCAN_CHUNK;
    int loc[8];
    int s = 0;
    #pragma unroll
    for (int k = 0; k < 8; ++k) {
        int idx = base + t * 8 + k;
        int v = (idx < n) ? cnt[idx] : 0;
        loc[k] = s; s += v;
    }
    sums[t] = s;
    __syncthreads();
    for (int off = 1; off < 256; off <<= 1) {
        int v = (t >= off) ? sums[t - off] : 0;
        __syncthreads();
        sums[t] += v;
        __syncthreads();
    }
    int off0 = bsum[b] + (sums[t] - s);
    #pragma unroll
    for (int k = 0; k < 8; ++k) {
        int idx = base + t * 8 + k;
        if (idx < n) row_start[idx] = off0 + loc[k];
    }
    if (b == gridDim.x - 1 && t == 255) row_start[n] = nnz;
}

__global__ void fill_kernel(const int* __restrict__ rows, const int* __restrict__ cols,
                            const float* __restrict__ vals, const int* __restrict__ row_start,
                            int* __restrict__ pos, uint2* __restrict__ eg, int nnz) {
    int i = blockIdx.x * blockDim.x + threadIdx.x;
    int stride = gridDim.x * blockDim.x;
    for (; i < nnz; i += stride) {
        int r = rows[i];
        int p = atomicAdd(&pos[r], 1);
        uint2 e;
        e.x = (unsigned)cols[i];           // col fits 19 bits; gather masks anyway
        e.y = __float_as_uint(vals[i]);
        eg[row_start[r] + p] = e;
    }
}

// ================= tier-3 fallback: scatter =================
__global__ __launch_bounds__(256) void base_neighbor_kernel(
    const float* __restrict__ users, const float* __restrict__ items,
    const int*   __restrict__ unb,   const float* __restrict__ uw,
    const int*   __restrict__ inb,   const float* __restrict__ iw,
    float* __restrict__ out)
{
    int gtid = blockIdx.x * blockDim.x + threadIdx.x;
    int row  = gtid >> 6;
    int lane = gtid & 63;
    if (row >= N_TOT) return;
    float acc;
    if (row < N_USER) {
        acc = users[(size_t)row * D + lane];
        const int*   nb = unb + (size_t)row * 10;
        const float* w  = uw  + (size_t)row * 10;
        #pragma unroll
        for (int q = 0; q < 10; ++q) acc += w[q] * users[(size_t)nb[q] * D + lane];
    } else {
        int r = row - N_USER;
        acc = items[(size_t)r * D + lane];
        const int*   nb = inb + (size_t)r * 10;
        const float* w  = iw  + (size_t)r * 10;
        #pragma unroll
        for (int q = 0; q < 10; ++q) acc += w[q] * items[(size_t)nb[q] * D + lane];
    }
    out[(size_t)row * D + lane] = acc;
}

__global__ __launch_bounds__(256) void edge_scatter_kernel(
    const float* __restrict__ users, const float* __restrict__ items,
    const int*   __restrict__ rows,  const int* __restrict__ cols,
    const float* __restrict__ vals,
    float* __restrict__ out, int nnz)
{
    int gtid = blockIdx.x * blockDim.x + threadIdx.x;
    int e    = gtid >> 6;
    int lane = gtid & 63;
    if (e >= nnz) return;
    int   r = rows[e];
    int   c = cols[e];
    float v = vals[e];
    const float* src = (c < N_USER) ? (users + (size_t)c * D)
                                    : (items + (size_t)(c - N_USER) * D);
    atomicAdd(&out[(size_t)r * D + lane], v * src[lane]);
}

extern "C" void kernel_launch(void* const* d_in, const int* in_sizes, int n_in,
                              void* d_out, int out_size, void* d_ws, size_t ws_size,
                              hipStream_t stream) {
    const float* users = (const float*)d_in[0];
    const float* items = (const float*)d_in[1];
    const int*   unb   = (const int*)  d_in[2];
    const float* uw    = (const float*)d_in[3];
    const int*   inb   = (const int*)  d_in[4];
    const float* iw    = (const float*)d_in[5];
    const int*   grow  = (const int*)  d_in[6];
    const int*   gcol  = (const int*)  d_in[7];
    const float* gval  = (const float*)d_in[8];
    float* out = (float*)d_out;

    const int nnz = in_sizes[6];

    const size_t A = 255;
    const size_t sz_eg       = (((size_t)nnz * 8) + A) & ~A;
    const size_t sz_eg2      = sz_eg;
    const size_t sz_hist     = (((size_t)NBLK_A * NB * 4) + A) & ~A;
    const size_t sz_tot      = (((size_t)NB * 4) + A) & ~A;
    const size_t sz_bstart   = (((size_t)(NB + 1) * 4) + A) & ~A;
    const size_t sz_rowstart = (((size_t)(N_TOT + 1) * 4) + A) & ~A;
    const size_t need1 = sz_eg + sz_eg2 + sz_hist + sz_tot + sz_bstart + sz_rowstart;

    const size_t sz_cnt  = (((size_t)N_TOT * 4) + A) & ~A;
    const int    nb2     = (N_TOT + SCAN_CHUNK - 1) / SCAN_CHUNK;
    const size_t sz_bsum = (((size_t)nb2 * 4) + A) & ~A;
    const size_t need2 = sz_eg + sz_rowstart + sz_cnt + sz_bsum;

    const int gather_grid = (int)(((long long)N_TOT * 64 + 255) / 256);

    if (ws_size >= need1) {
        char* wsp = (char*)d_ws;
        uint2* eg        = (uint2*)wsp;  wsp += sz_eg;
        uint2* eg2       = (uint2*)wsp;  wsp += sz_eg2;
        int*   hist      = (int*)wsp;    wsp += sz_hist;
        int*   tot       = (int*)wsp;    wsp += sz_tot;
        int*   bstart    = (int*)wsp;    wsp += sz_bstart;
        int*   row_start = (int*)wsp;

        const int chunk = (nnz + NBLK_A - 1) / NBLK_A;

        hist_kernel<<<NBLK_A, THR_A, 0, stream>>>(grow, hist, nnz, chunk);
        bucket_tot_kernel<<<(NB + 255) / 256, 256, 0, stream>>>(hist, tot);
        scan_kernel<<<1, 1024, 0, stream>>>(tot, bstart, nnz);
        blockbase_kernel<<<(NB + 255) / 256, 256, 0, stream>>>(hist, bstart);
        bin_kernel<<<NBLK_A, THR_A, 0, stream>>>(grow, gcol, gval, hist, eg, nnz, chunk);
        rowsort_kernel<<<NB, 256, 0, stream>>>(eg, bstart, eg2, row_start, nnz);
        gather_kernel<<<gather_grid, 256, 0, stream>>>(users, items, unb, uw, inb, iw,
                                                       row_start, eg2, out);
    } else if (ws_size >= need2) {
        char* wsp = (char*)d_ws;
        uint2* eg        = (uint2*)wsp;  wsp += sz_eg;
        int*   row_start = (int*)wsp;    wsp += sz_rowstart;
        int*   cnt       = (int*)wsp;    wsp += sz_cnt;
        int*   bsum      = (int*)wsp;

        hipMemsetAsync(cnt, 0, (size_t)N_TOT * 4, stream);
        count_kernel<<<2048, 256, 0, stream>>>(grow, cnt, nnz);
        scan_block_sums<<<nb2, 256, 0, stream>>>(cnt, bsum, N_TOT);
        scan_bsum_kernel<<<1, 64, 0, stream>>>(bsum, nb2);
        scan_final<<<nb2, 256, 0, stream>>>(cnt, bsum, row_start, N_TOT, nnz);
        hipMemsetAsync(cnt, 0, (size_t)N_TOT * 4, stream);
        fill_kernel<<<2048, 256, 0, stream>>>(grow, gcol, gval, row_start, cnt, eg, nnz);
        gather_kernel<<<gather_grid, 256, 0, stream>>>(users, items, unb, uw, inb, iw,
                                                       row_start, eg, out);
    } else {
        base_neighbor_kernel<<<gather_grid, 256, 0, stream>>>(users, items, unb, uw, inb, iw, out);
        long long ethreads = (long long)nnz * 64;
        long long egrid = (ethreads + 255) / 256;
        edge_scatter_kernel<<<(int)egrid, 256, 0, stream>>>(users, items, grow, gcol, gval, out, nnz);
    }
}

// Round 5
// 800.617 us; speedup vs baseline: 4.5611x; 1.2737x over previous
//
#include <hip/hip_runtime.h>

#define N_USER 100000
#define N_ITEM 200000
#define N_TOT  (N_USER + N_ITEM)
#define D      64
#define RPB    64                        // rows per bucket
#define NB     ((N_TOT + RPB - 1) / RPB) // 4688 buckets
#define NBLK_A 256                       // blocks for hist/bin passes
#define THR_A  512
#define SCAN_CHUNK 2048                  // tier-2 scan: 256 threads x 8

// ================= tier-1: bucket binning =================

__global__ __launch_bounds__(THR_A) void hist_kernel(const int* __restrict__ rows,
                                                     int* __restrict__ hist, int nnz, int chunk) {
    __shared__ int h[NB];
    for (int k = threadIdx.x; k < NB; k += blockDim.x) h[k] = 0;
    __syncthreads();
    int lo = blockIdx.x * chunk;
    int hi = min(lo + chunk, nnz);
    for (int i = lo + threadIdx.x; i < hi; i += blockDim.x)
        atomicAdd(&h[rows[i] >> 6], 1);
    __syncthreads();
    for (int k = threadIdx.x; k < NB; k += blockDim.x)
        hist[(size_t)blockIdx.x * NB + k] = h[k];
}

__global__ void bucket_tot_kernel(const int* __restrict__ hist, int* __restrict__ tot) {
    int k = blockIdx.x * blockDim.x + threadIdx.x;
    if (k >= NB) return;
    int s = 0;
    for (int b = 0; b < NBLK_A; ++b) s += hist[(size_t)b * NB + k];
    tot[k] = s;
}

__global__ __launch_bounds__(1024) void scan_kernel(const int* __restrict__ tot,
                                                    int* __restrict__ bstart, int nnz) {
    __shared__ int s[1024];
    const int t = threadIdx.x;
    const int PER = (NB + 1023) / 1024;   // 5
    int loc[8];
    int sum = 0;
    #pragma unroll
    for (int k = 0; k < PER; ++k) {
        int idx = t * PER + k;
        int v = (idx < NB) ? tot[idx] : 0;
        loc[k] = sum; sum += v;
    }
    s[t] = sum;
    __syncthreads();
    for (int off = 1; off < 1024; off <<= 1) {
        int v = (t >= off) ? s[t - off] : 0;
        __syncthreads();
        s[t] += v;
        __syncthreads();
    }
    int base = s[t] - sum;  // exclusive
    #pragma unroll
    for (int k = 0; k < PER; ++k) {
        int idx = t * PER + k;
        if (idx < NB) bstart[idx] = base + loc[k];
    }
    if (t == 1023) bstart[NB] = nnz;
}

__global__ void blockbase_kernel(int* __restrict__ hist, const int* __restrict__ bstart) {
    int k = blockIdx.x * blockDim.x + threadIdx.x;
    if (k >= NB) return;
    int base = bstart[k];
    for (int b = 0; b < NBLK_A; ++b) {
        size_t idx = (size_t)b * NB + k;
        int v = hist[idx];
        hist[idx] = base;
        base += v;
    }
}

__global__ __launch_bounds__(THR_A) void bin_kernel(const int* __restrict__ rows,
                                                    const int* __restrict__ cols,
                                                    const float* __restrict__ vals,
                                                    const int* __restrict__ hist,
                                                    uint2* __restrict__ eg, int nnz, int chunk) {
    __shared__ int cur[NB];
    for (int k = threadIdx.x; k < NB; k += blockDim.x)
        cur[k] = hist[(size_t)blockIdx.x * NB + k];
    __syncthreads();
    int lo = blockIdx.x * chunk;
    int hi = min(lo + chunk, nnz);
    for (int i = lo + threadIdx.x; i < hi; i += blockDim.x) {
        int r = rows[i];
        int k = r >> 6;
        int slot = atomicAdd(&cur[k], 1);
        uint2 p;
        p.x = ((unsigned)(r & 63) << 19) | (unsigned)cols[i];
        p.y = __float_as_uint(vals[i]);
        eg[slot] = p;
    }
}

// per-bucket row sort: LDS hist -> 64-lane scan -> scatter to eg2 + row_start
__global__ __launch_bounds__(256) void rowsort_kernel(
    const uint2* __restrict__ eg, const int* __restrict__ bstart,
    uint2* __restrict__ eg2, int* __restrict__ row_start, int nnz)
{
    __shared__ int h[RPB];
    __shared__ int cur[RPB];
    const int k   = blockIdx.x;
    const int tid = threadIdx.x;
    const int s   = bstart[k];
    const int e   = bstart[k + 1];

    if (tid < RPB) h[tid] = 0;
    __syncthreads();
    for (int i = s + tid; i < e; i += 256)
        atomicAdd(&h[eg[i].x >> 19], 1);
    __syncthreads();
    if (tid < RPB) {   // wave 0 only
        int orig = h[tid];
        int v = orig;
        #pragma unroll
        for (int off = 1; off < RPB; off <<= 1) {
            int u = __shfl_up(v, off);
            if (tid >= off) v += u;
        }
        int excl = v - orig;
        cur[tid] = excl;
        int row = k * RPB + tid;
        if (row < N_TOT) row_start[row] = s + excl;
    }
    __syncthreads();
    for (int i = s + tid; i < e; i += 256) {
        uint2 p = eg[i];
        int ro = (int)(p.x >> 19);
        int slot = atomicAdd(&cur[ro], 1);
        eg2[s + slot] = p;
    }
    if (k == NB - 1 && tid == 0) row_start[N_TOT] = nnz;
}

// ================= fused gather: 16 lanes per row, float4 per lane =================
__global__ __launch_bounds__(256) void gather16_kernel(
    const float* __restrict__ users, const float* __restrict__ items,
    const int*   __restrict__ unb,   const float* __restrict__ uw,
    const int*   __restrict__ inb,   const float* __restrict__ iw,
    const int*   __restrict__ row_start, const uint2* __restrict__ eg,
    float* __restrict__ out)
{
    const int tid = threadIdx.x;
    const int grp = tid >> 4;          // 16 rows per block
    const int sub = tid & 15;
    const int row = blockIdx.x * 16 + grp;
    if (row >= N_TOT) return;
    const int d0 = sub * 4;

    float4 acc;
    if (row < N_USER) {
        acc = *reinterpret_cast<const float4*>(&users[(size_t)row * D + d0]);
        const int*   nb = unb + (size_t)row * 10;
        const float* w  = uw  + (size_t)row * 10;
        #pragma unroll
        for (int q = 0; q < 10; ++q) {
            float4 v = *reinterpret_cast<const float4*>(&users[(size_t)nb[q] * D + d0]);
            float wq = w[q];
            acc.x += wq * v.x; acc.y += wq * v.y; acc.z += wq * v.z; acc.w += wq * v.w;
        }
    } else {
        int r = row - N_USER;
        acc = *reinterpret_cast<const float4*>(&items[(size_t)r * D + d0]);
        const int*   nb = inb + (size_t)r * 10;
        const float* w  = iw  + (size_t)r * 10;
        #pragma unroll
        for (int q = 0; q < 10; ++q) {
            float4 v = *reinterpret_cast<const float4*>(&items[(size_t)nb[q] * D + d0]);
            float wq = w[q];
            acc.x += wq * v.x; acc.y += wq * v.y; acc.z += wq * v.z; acc.w += wq * v.w;
        }
    }

    const int s = row_start[row];
    const int e = row_start[row + 1];
    int i = s;
    for (; i + 3 < e; i += 4) {
        uint2 p0 = eg[i], p1 = eg[i + 1], p2 = eg[i + 2], p3 = eg[i + 3];
        int c0 = (int)(p0.x & 0x7FFFFu), c1 = (int)(p1.x & 0x7FFFFu);
        int c2 = (int)(p2.x & 0x7FFFFu), c3 = (int)(p3.x & 0x7FFFFu);
        const float* s0 = (c0 < N_USER) ? users + (size_t)c0 * D : items + (size_t)(c0 - N_USER) * D;
        const float* s1 = (c1 < N_USER) ? users + (size_t)c1 * D : items + (size_t)(c1 - N_USER) * D;
        const float* s2 = (c2 < N_USER) ? users + (size_t)c2 * D : items + (size_t)(c2 - N_USER) * D;
        const float* s3 = (c3 < N_USER) ? users + (size_t)c3 * D : items + (size_t)(c3 - N_USER) * D;
        float4 v0 = *reinterpret_cast<const float4*>(s0 + d0);
        float4 v1 = *reinterpret_cast<const float4*>(s1 + d0);
        float4 v2 = *reinterpret_cast<const float4*>(s2 + d0);
        float4 v3 = *reinterpret_cast<const float4*>(s3 + d0);
        float a0 = __uint_as_float(p0.y), a1 = __uint_as_float(p1.y);
        float a2 = __uint_as_float(p2.y), a3 = __uint_as_float(p3.y);
        acc.x += a0 * v0.x; acc.y += a0 * v0.y; acc.z += a0 * v0.z; acc.w += a0 * v0.w;
        acc.x += a1 * v1.x; acc.y += a1 * v1.y; acc.z += a1 * v1.z; acc.w += a1 * v1.w;
        acc.x += a2 * v2.x; acc.y += a2 * v2.y; acc.z += a2 * v2.z; acc.w += a2 * v2.w;
        acc.x += a3 * v3.x; acc.y += a3 * v3.y; acc.z += a3 * v3.z; acc.w += a3 * v3.w;
    }
    for (; i < e; ++i) {
        uint2 p = eg[i];
        int c = (int)(p.x & 0x7FFFFu);
        const float* src = (c < N_USER) ? users + (size_t)c * D : items + (size_t)(c - N_USER) * D;
        float4 v = *reinterpret_cast<const float4*>(src + d0);
        float a = __uint_as_float(p.y);
        acc.x += a * v.x; acc.y += a * v.y; acc.z += a * v.z; acc.w += a * v.w;
    }

    *reinterpret_cast<float4*>(&out[(size_t)row * D + d0]) = acc;
}

// ================= tier-2: round-2 CSR build + 64-lane gather =================

__global__ void count_kernel(const int* __restrict__ rows, int* __restrict__ cnt, int nnz) {
    int i = blockIdx.x * blockDim.x + threadIdx.x;
    int stride = gridDim.x * blockDim.x;
    for (; i < nnz; i += stride) atomicAdd(&cnt[rows[i]], 1);
}

__global__ void scan_block_sums(const int* __restrict__ cnt, int* __restrict__ bsum, int n) {
    __shared__ int sdata[256];
    int base = blockIdx.x * SCAN_CHUNK;
    int s = 0;
    for (int t = threadIdx.x; t < SCAN_CHUNK; t += 256) {
        int idx = base + t;
        s += (idx < n) ? cnt[idx] : 0;
    }
    sdata[threadIdx.x] = s;
    __syncthreads();
    for (int off = 128; off > 0; off >>= 1) {
        if (threadIdx.x < off) sdata[threadIdx.x] += sdata[threadIdx.x + off];
        __syncthreads();
    }
    if (threadIdx.x == 0) bsum[blockIdx.x] = sdata[0];
}

__global__ void scan_bsum_kernel(int* __restrict__ bsum, int nb) {
    if (threadIdx.x == 0 && blockIdx.x == 0) {
        int acc = 0;
        for (int i = 0; i < nb; ++i) { int v = bsum[i]; bsum[i] = acc; acc += v; }
    }
}

__global__ void scan_final(const int* __restrict__ cnt, const int* __restrict__ bsum,
                           int* __restrict__ row_start, int n, int nnz) {
    __shared__ int sums[256];
    int b = blockIdx.x, t = threadIdx.x;
    int base = b * SCAN_CHUNK;
    int loc[8];
    int s = 0;
    #pragma unroll
    for (int k = 0; k < 8; ++k) {
        int idx = base + t * 8 + k;
        int v = (idx < n) ? cnt[idx] : 0;
        loc[k] = s; s += v;
    }
    sums[t] = s;
    __syncthreads();
    for (int off = 1; off < 256; off <<= 1) {
        int v = (t >= off) ? sums[t - off] : 0;
        __syncthreads();
        sums[t] += v;
        __syncthreads();
    }
    int off0 = bsum[b] + (sums[t] - s);
    #pragma unroll
    for (int k = 0; k < 8; ++k) {
        int idx = base + t * 8 + k;
        if (idx < n) row_start[idx] = off0 + loc[k];
    }
    if (b == gridDim.x - 1 && t == 255) row_start[n] = nnz;
}

__global__ void fill_kernel(const int* __restrict__ rows, const int* __restrict__ cols,
                            const float* __restrict__ vals, const int* __restrict__ row_start,
                            int* __restrict__ pos, uint2* __restrict__ eg, int nnz) {
    int i = blockIdx.x * blockDim.x + threadIdx.x;
    int stride = gridDim.x * blockDim.x;
    for (; i < nnz; i += stride) {
        int r = rows[i];
        int p = atomicAdd(&pos[r], 1);
        uint2 e;
        e.x = (unsigned)cols[i];
        e.y = __float_as_uint(vals[i]);
        eg[row_start[r] + p] = e;
    }
}

// ================= tier-3 fallback: scatter =================
__global__ __launch_bounds__(256) void base_neighbor_kernel(
    const float* __restrict__ users, const float* __restrict__ items,
    const int*   __restrict__ unb,   const float* __restrict__ uw,
    const int*   __restrict__ inb,   const float* __restrict__ iw,
    float* __restrict__ out)
{
    int gtid = blockIdx.x * blockDim.x + threadIdx.x;
    int row  = gtid >> 6;
    int lane = gtid & 63;
    if (row >= N_TOT) return;
    float acc;
    if (row < N_USER) {
        acc = users[(size_t)row * D + lane];
        const int*   nb = unb + (size_t)row * 10;
        const float* w  = uw  + (size_t)row * 10;
        #pragma unroll
        for (int q = 0; q < 10; ++q) acc += w[q] * users[(size_t)nb[q] * D + lane];
    } else {
        int r = row - N_USER;
        acc = items[(size_t)r * D + lane];
        const int*   nb = inb + (size_t)r * 10;
        const float* w  = iw  + (size_t)r * 10;
        #pragma unroll
        for (int q = 0; q < 10; ++q) acc += w[q] * items[(size_t)nb[q] * D + lane];
    }
    out[(size_t)row * D + lane] = acc;
}

__global__ __launch_bounds__(256) void edge_scatter_kernel(
    const float* __restrict__ users, const float* __restrict__ items,
    const int*   __restrict__ rows,  const int* __restrict__ cols,
    const float* __restrict__ vals,
    float* __restrict__ out, int nnz)
{
    int gtid = blockIdx.x * blockDim.x + threadIdx.x;
    int e    = gtid >> 6;
    int lane = gtid & 63;
    if (e >= nnz) return;
    int   r = rows[e];
    int   c = cols[e];
    float v = vals[e];
    const float* src = (c < N_USER) ? (users + (size_t)c * D)
                                    : (items + (size_t)(c - N_USER) * D);
    atomicAdd(&out[(size_t)r * D + lane], v * src[lane]);
}

extern "C" void kernel_launch(void* const* d_in, const int* in_sizes, int n_in,
                              void* d_out, int out_size, void* d_ws, size_t ws_size,
                              hipStream_t stream) {
    const float* users = (const float*)d_in[0];
    const float* items = (const float*)d_in[1];
    const int*   unb   = (const int*)  d_in[2];
    const float* uw    = (const float*)d_in[3];
    const int*   inb   = (const int*)  d_in[4];
    const float* iw    = (const float*)d_in[5];
    const int*   grow  = (const int*)  d_in[6];
    const int*   gcol  = (const int*)  d_in[7];
    const float* gval  = (const float*)d_in[8];
    float* out = (float*)d_out;

    const int nnz = in_sizes[6];

    const size_t A = 255;
    const size_t sz_eg       = (((size_t)nnz * 8) + A) & ~A;
    const size_t sz_eg2      = sz_eg;
    const size_t sz_hist     = (((size_t)NBLK_A * NB * 4) + A) & ~A;
    const size_t sz_tot      = (((size_t)NB * 4) + A) & ~A;
    const size_t sz_bstart   = (((size_t)(NB + 1) * 4) + A) & ~A;
    const size_t sz_rowstart = (((size_t)(N_TOT + 1) * 4) + A) & ~A;
    const size_t need1 = sz_eg + sz_eg2 + sz_hist + sz_tot + sz_bstart + sz_rowstart;

    const size_t sz_cnt  = (((size_t)N_TOT * 4) + A) & ~A;
    const int    nb2     = (N_TOT + SCAN_CHUNK - 1) / SCAN_CHUNK;
    const size_t sz_bsum = (((size_t)nb2 * 4) + A) & ~A;
    const size_t need2 = sz_eg + sz_rowstart + sz_cnt + sz_bsum;

    const int g16_grid = (N_TOT + 15) / 16;

    if (ws_size >= need1) {
        char* wsp = (char*)d_ws;
        uint2* eg        = (uint2*)wsp;  wsp += sz_eg;
        uint2* eg2       = (uint2*)wsp;  wsp += sz_eg2;
        int*   hist      = (int*)wsp;    wsp += sz_hist;
        int*   tot       = (int*)wsp;    wsp += sz_tot;
        int*   bstart    = (int*)wsp;    wsp += sz_bstart;
        int*   row_start = (int*)wsp;

        const int chunk = (nnz + NBLK_A - 1) / NBLK_A;

        hist_kernel<<<NBLK_A, THR_A, 0, stream>>>(grow, hist, nnz, chunk);
        bucket_tot_kernel<<<(NB + 255) / 256, 256, 0, stream>>>(hist, tot);
        scan_kernel<<<1, 1024, 0, stream>>>(tot, bstart, nnz);
        blockbase_kernel<<<(NB + 255) / 256, 256, 0, stream>>>(hist, bstart);
        bin_kernel<<<NBLK_A, THR_A, 0, stream>>>(grow, gcol, gval, hist, eg, nnz, chunk);
        rowsort_kernel<<<NB, 256, 0, stream>>>(eg, bstart, eg2, row_start, nnz);
        gather16_kernel<<<g16_grid, 256, 0, stream>>>(users, items, unb, uw, inb, iw,
                                                      row_start, eg2, out);
    } else if (ws_size >= need2) {
        char* wsp = (char*)d_ws;
        uint2* eg        = (uint2*)wsp;  wsp += sz_eg;
        int*   row_start = (int*)wsp;    wsp += sz_rowstart;
        int*   cnt       = (int*)wsp;    wsp += sz_cnt;
        int*   bsum      = (int*)wsp;

        hipMemsetAsync(cnt, 0, (size_t)N_TOT * 4, stream);
        count_kernel<<<2048, 256, 0, stream>>>(grow, cnt, nnz);
        scan_block_sums<<<nb2, 256, 0, stream>>>(cnt, bsum, N_TOT);
        scan_bsum_kernel<<<1, 64, 0, stream>>>(bsum, nb2);
        scan_final<<<nb2, 256, 0, stream>>>(cnt, bsum, row_start, N_TOT, nnz);
        hipMemsetAsync(cnt, 0, (size_t)N_TOT * 4, stream);
        fill_kernel<<<2048, 256, 0, stream>>>(grow, gcol, gval, row_start, cnt, eg, nnz);
        gather16_kernel<<<g16_grid, 256, 0, stream>>>(users, items, unb, uw, inb, iw,
                                                      row_start, eg, out);
    } else {
        int grid = (int)(((long long)N_TOT * 64 + 255) / 256);
        base_neighbor_kernel<<<grid, 256, 0, stream>>>(users, items, unb, uw, inb, iw, out);
        long long ethreads = (long long)nnz * 64;
        long long egrid = (ethreads + 255) / 256;
        edge_scatter_kernel<<<(int)egrid, 256, 0, stream>>>(users, items, grow, gcol, gval, out, nnz);
    }
}